// Round 2
// baseline (290.122 us; speedup 1.0000x reference)
//
#include <hip/hip_runtime.h>

// CNOT on wires (control=0, target=1) of a 13-qubit (DIM=2) state, batch 64.
// U is a permutation matrix: basis index j maps to j ^ ((j>>12 & 1) << 11)
// (flip target bit 11 iff control bit 12 set). CNOT is an involution, so
// out[i, :] = x[i ^ ((i>>12&1)<<11), :] — a pure row gather. U is never read.
//
// HARNESS DTYPE NOTE (round-0/1 evidence): complex64 tensors are lowered to
// bfloat16 with real/imag interleaved. x/out are (8192, 64) complex ->
// 8192 rows x 128 bf16 = 256 B/row. out_size = 1,048,576 bf16 = 2 MB.
// Round-1 core dump was a 4 MB (complex64-sized) write into this 2 MB buffer.
//
// One row = 256 B = 16 float4. Each thread moves one float4 (8 bf16 = 4
// complex amplitudes). 131,072 threads total; 2 MB read + 2 MB write.
// Pure byte copy -> bit-exact vs the np reference (U entries are 0/1).

#define DHILB 8192
#define ROW_F4 16                      // 256 B per row / 16 B per float4
#define TOTAL_F4 (DHILB * ROW_F4)      // 131072

__global__ __launch_bounds__(256)
void cnot_permute_rows_bf16(const float4* __restrict__ x, float4* __restrict__ out) {
    const int tid = blockIdx.x * blockDim.x + threadIdx.x;  // grid sized exactly
    const int row = tid >> 4;          // basis-state index (output row)
    const int col = tid & 15;          // float4 within the 256 B row
    // involution: source row = row with target bit 11 flipped iff control bit 12 set
    const int src = row ^ (((row >> 12) & 1) << 11);
    out[(row << 4) | col] = x[(src << 4) | col];
}

extern "C" void kernel_launch(void* const* d_in, const int* in_sizes, int n_in,
                              void* d_out, int out_size, void* d_ws, size_t ws_size,
                              hipStream_t stream) {
    // d_in[0] = U (8192x8192 complex, bf16-lowered) -- unused, permutation known
    // d_in[1] = x (8192x64 complex, bf16-lowered, 1,048,576 bf16 elements)
    const float4* x = (const float4*)d_in[1];
    float4* out = (float4*)d_out;

    const int threads = 256;
    const int blocks = TOTAL_F4 / threads;  // 512
    cnot_permute_rows_bf16<<<blocks, threads, 0, stream>>>(x, out);
}